// Round 13
// baseline (313.146 us; speedup 1.0000x reference)
//
#include <hip/hip_runtime.h>

#define B_ 8
#define D_ 256
#define T_ 2048
#define K_ 8192
#define N_ (B_*T_)              // 16384 tokens

typedef _Float16 half8 __attribute__((ext_vector_type(8)));
typedef float f32x4 __attribute__((ext_vector_type(4)));

constexpr int KPART  = 1024;          // codes per partition
constexpr int NPART  = 8;
constexpr int CAP_P  = 64;            // candidate slots per (token, partition)
constexpr float MARGIN = 6.0f;        // validated rounds 4-12 (cross-lane gate)
constexpr int   QTHR   = 78;          // rescore filter (9.75 * 8), validated
constexpr float CSCALE = 16384.0f;    // 2^14 codebook scale

// A image: 64-token chunks: q=n>>6 -> q*16384 + st*4096 + kb*512 + frag
// B image: 32-code chunks:  q=k>>5 -> q*8192 + ((k>>4)&1)*4096 + kb*512 + frag
// frag: ((d>>3)&3)*128 + row*8 + (d&7)   (16x16x32 f16 fragment order)

// ------------------------------------------------------------------
// 1) prep: blocks [0,256): xnorm + fp16(2x) A-image + xT fp32 rows
//          blocks [256,1280): fp16(c * 2^14) B fragment image
// ------------------------------------------------------------------
__global__ __launch_bounds__(256) void prep_k(const float* __restrict__ x,
                                              const float* __restrict__ cb,
                                              _Float16* __restrict__ Xh,
                                              _Float16* __restrict__ Ch,
                                              float* __restrict__ xT,
                                              float* __restrict__ xn) {
    const int tid = threadIdx.x;
    if (blockIdx.x >= 256) {
        const int task = (blockIdx.x - 256) * 256 + tid;   // K*32 tasks
        const int k = task >> 5, d0 = (task & 31) * 8;
        const float4 v0 = *(const float4*)(cb + (size_t)k * D_ + d0);
        const float4 v1 = *(const float4*)(cb + (size_t)k * D_ + d0 + 4);
        const float vv[8] = {v0.x, v0.y, v0.z, v0.w, v1.x, v1.y, v1.z, v1.w};
        half8 hi;
        #pragma unroll
        for (int j = 0; j < 8; ++j) hi[j] = (_Float16)(vv[j] * CSCALE);
        const size_t a = (size_t)(k >> 5) * 8192 + (size_t)((k >> 4) & 1) * 4096
                       + (size_t)(d0 >> 5) * 512
                       + (size_t)(((d0 >> 3) & 3) * 16 + (k & 15)) * 8;
        *(half8*)(Ch + a) = hi;
        return;
    }
    __shared__ float red[4][64];
    const int n0 = blockIdx.x * 64;          // one 64-token A-chunk per block
    const int b = n0 >> 11, t0 = n0 & 2047;
    const int tt = tid & 63, dg = tid >> 6;
    const int n = n0 + tt;
    const float* p = x + (size_t)b * (D_ * T_) + t0 + tt;
    _Float16* xbase = Xh + (size_t)blockIdx.x * 16384
                    + (size_t)((tt >> 4) & 3) * 4096 + (size_t)(tt & 15) * 8;
    float s = 0.f;
    for (int it = 0; it < 8; ++it) {
        const int d0 = dg * 64 + it * 8;
        float vv[8];
        half8 hi;
        #pragma unroll
        for (int j = 0; j < 8; ++j) {
            const float v = p[(size_t)(d0 + j) * T_];
            s = fmaf(v, v, s);
            vv[j] = v;
            hi[j] = (_Float16)(2.0f * v);
        }
        *(half8*)(xbase + (size_t)(d0 >> 5) * 512 + (size_t)((d0 >> 3) & 3) * 128) = hi;
        *(float4*)(xT + (size_t)n * D_ + d0)     = (float4){vv[0], vv[1], vv[2], vv[3]};
        *(float4*)(xT + (size_t)n * D_ + d0 + 4) = (float4){vv[4], vv[5], vv[6], vv[7]};
    }
    red[dg][tt] = s;
    __syncthreads();
    if (tid < 64) xn[n0 + tt] = (red[0][tt] + red[1][tt]) + (red[2][tt] + red[3][tt]);
}

// ------------------------------------------------------------------
// 2) main: wave-autonomous reg-streaming scorer (r8 structure) at
//    32 tokens/wave -> 4096 waves = 4 waves/SIMD (latency hiding x2).
//    4 waves/block share kp and B-stream order -> L1 reuse. No barriers.
// ------------------------------------------------------------------
__global__ __launch_bounds__(256, 4) void argmin_mfma(const _Float16* __restrict__ XhT,
                                                      const _Float16* __restrict__ ChT,
                                                      int* __restrict__ cntP,
                                                      unsigned int* __restrict__ cand) {
    __shared__ int lcnt[128];

    const int tid = threadIdx.x;
    const int lane = tid & 63, wave = tid >> 6;
    const int l15 = lane & 15, l4 = lane >> 4;
    const int kp = blockIdx.x & 7;       // same-kp blocks -> same XCD (L2 affinity)
    const int tt = blockIdx.x >> 3;      // 128 token tiles of 128
    const int n0b = tt * 128;
    const int qA = tt * 2 + (wave >> 1); // wave's 64-token A chunk
    const int stb = (wave & 1) * 2;      // subtile base (2 subtiles = 32 tokens)

    // ---- token fragments in registers: 32 tokens x 256 d (64 VGPR) ----
    half8 ah[2][8];
    #pragma unroll
    for (int st = 0; st < 2; ++st)
        #pragma unroll
        for (int kb = 0; kb < 8; ++kb)
            ah[st][kb] = *(const half8*)(XhT + (size_t)qA * 16384
                                         + (size_t)(stb + st) * 4096
                                         + (size_t)kb * 512 + (size_t)lane * 8);

    if (tid < 128) lcnt[tid] = 0;
    __syncthreads();

    float runmax[2];
    #pragma unroll
    for (int st = 0; st < 2; ++st) runmax[st] = -3.4e38f;

    const _Float16* cB = ChT + (size_t)(kp * 32) * 8192 + (size_t)lane * 8;

    // slice loader: 16 codes x 256 d -> 8 coalesced 16B reg loads
    auto LB = [&](half8* bf, size_t off) {
        #pragma unroll
        for (int kb = 0; kb < 8; ++kb)
            bf[kb] = *(const half8*)(cB + off + (size_t)kb * 512);
    };
    // MFMA: D[code][token]; code row = l4*4+r, token col = l15
    auto MM = [&](f32x4* acc, const half8* bf) {
        #pragma unroll
        for (int st = 0; st < 2; ++st) acc[st] = (f32x4){0.f, 0.f, 0.f, 0.f};
        __builtin_amdgcn_s_setprio(1);
        #pragma unroll
        for (int kb = 0; kb < 8; ++kb)
            #pragma unroll
            for (int st = 0; st < 2; ++st)
                acc[st] = __builtin_amdgcn_mfma_f32_16x16x32_f16(bf[kb], ah[st][kb], acc[st], 0, 0, 0);
        __builtin_amdgcn_s_setprio(0);
    };
    // validated gate: per-token (cross-lane) running max, MARGIN 6
    auto EPI = [&](const f32x4* acc, int s) {
        const int kbase = kp * KPART + s * 16 + l4 * 4;
        #pragma unroll
        for (int st = 0; st < 2; ++st) {
            const float lm = fmaxf(fmaxf(acc[st][0], acc[st][1]),
                                   fmaxf(acc[st][2], acc[st][3]));
            float m = fmaxf(lm, __shfl_xor(lm, 16));
            m = fmaxf(m, __shfl_xor(m, 32));
            runmax[st] = fmaxf(runmax[st], m);
            const float thr = runmax[st] - MARGIN;
            if (lm >= thr) {                      // rare: lane has a candidate
                const int ltok = wave * 32 + st * 16 + l15;
                #pragma unroll
                for (int r = 0; r < 4; ++r) {
                    const float v = acc[st][r];
                    if (v >= thr) {
                        const int pos = atomicAdd(&lcnt[ltok], 1);
                        if (pos < CAP_P) {
                            int q = (int)floorf((v + 2048.0f) * 8.0f);
                            q = q < 0 ? 0 : (q > 32767 ? 32767 : q);
                            cand[((size_t)(kp * N_ + n0b + ltok)) * CAP_P + pos] =
                                ((unsigned int)q << 13) | (unsigned int)(kbase + r);
                        }
                    }
                }
            }
        }
    };

    half8 bA[8], bB[8];
    f32x4 acc[2];
    LB(bA, 0);                                   // slice 0
    for (int g = 0; g < 32; ++g) {               // 2 slices per group
        const size_t bg = (size_t)g * 8192;
        LB(bB, bg + 4096);                       // prefetch slice 2g+1
        MM(acc, bA);
        EPI(acc, 2 * g);
        if (g < 31) LB(bA, bg + 8192);           // prefetch slice 2g+2
        MM(acc, bB);
        EPI(acc, 2 * g + 1);
    }

    __syncthreads();
    if (tid < 128) cntP[kp * N_ + n0b + tid] = lcnt[tid];
}

// ------------------------------------------------------------------
// 3) rescore: lane-parallel candidate load (slot==lane), qmax filter,
//    ballot-compacted survivors, exact fp32 fl(xnorm - dot2), tie->lowest k
// ------------------------------------------------------------------
__global__ __launch_bounds__(256) void rescore_k(const float* __restrict__ xT,
                                                 const float* __restrict__ cb,
                                                 const float* __restrict__ xn,
                                                 const int* __restrict__ cntP,
                                                 const unsigned int* __restrict__ cand,
                                                 float* __restrict__ codes_out,
                                                 int* __restrict__ hist) {
    const int tid = threadIdx.x, lane = tid & 63, wave = tid >> 6;
    const int n = blockIdx.x * 4 + wave;     // one wave per token
    float xv[4];
    #pragma unroll
    for (int j = 0; j < 4; ++j) xv[j] = 2.0f * xT[(size_t)n * D_ + lane + j * 64];
    const float xnr = xn[n];

    unsigned int w[NPART];
    int mc[NPART];
    int qm = 0;
    #pragma unroll
    for (int kp = 0; kp < NPART; ++kp) {
        int m = cntP[kp * N_ + n]; m = m > CAP_P ? CAP_P : m;
        mc[kp] = m;
        unsigned int v = 0;
        if (lane < m) v = cand[((size_t)(kp * N_ + n)) * CAP_P + lane];   // coalesced
        w[kp] = v;
        const int q = (int)(v >> 13);
        qm = q > qm ? q : qm;
    }
    #pragma unroll
    for (int s = 1; s < 64; s <<= 1) {
        const int o = __shfl_xor(qm, s);
        qm = o > qm ? o : qm;
    }
    const int qthr = qm - QTHR;

    float bs = 3.4e38f; int bk = 0x7fffffff;
    #pragma unroll
    for (int kp = 0; kp < NPART; ++kp) {
        unsigned long long mask = __ballot(lane < mc[kp] && (int)(w[kp] >> 13) >= qthr);
        while (mask) {
            const int j = __builtin_ctzll(mask);
            mask &= mask - 1;
            const unsigned int pk = __shfl(w[kp], j);
            const int k = (int)(pk & 8191u);
            const float* cr = cb + (size_t)k * D_;
            float p = 0.f;
            #pragma unroll
            for (int j2 = 0; j2 < 4; ++j2) p = fmaf(xv[j2], cr[lane + j2 * 64], p);
            #pragma unroll
            for (int s = 1; s < 64; s <<= 1) p += __shfl_xor(p, s);
            const float sc = xnr - p;
            if (sc < bs || (sc == bs && k < bk)) { bs = sc; bk = k; }
        }
    }
    if (lane == 0) {
        codes_out[n] = (float)bk;
        atomicAdd(&hist[bk], 1);
    }
}

// ------------------------------------------------------------------
// 4) gather quantized (+ straight-through x+(q-x)), MSE partials.
//    Codebook rows staged in LDS (coalesced) to kill scattered gathers.
// ------------------------------------------------------------------
__global__ __launch_bounds__(256) void gather_k(const float* __restrict__ x,
                                                const float* __restrict__ cb,
                                                const float* __restrict__ codes_f,
                                                float* __restrict__ out_q,
                                                float* __restrict__ msep) {
    __shared__ int codes_s[64];
    __shared__ float cbs[64][65];
    __shared__ float red[256];
    const int tq = blockIdx.x >> 2;      // token 64-chunk
    const int dq = blockIdx.x & 3;       // d quarter (64 d's)
    const int n0 = tq * 64;
    const int b = n0 >> 11, t0 = n0 & 2047;
    const int tid = threadIdx.x;
    if (tid < 64) codes_s[tid] = (int)codes_f[n0 + tid];
    __syncthreads();
    {
        const int rr0 = tid >> 4, c4 = (tid & 15) * 4;
        #pragma unroll
        for (int rr = rr0; rr < 64; rr += 16) {
            const float4 v = *(const float4*)(cb + (size_t)codes_s[rr] * D_ + dq * 64 + c4);
            cbs[rr][c4 + 0] = v.x; cbs[rr][c4 + 1] = v.y;
            cbs[rr][c4 + 2] = v.z; cbs[rr][c4 + 3] = v.w;
        }
    }
    __syncthreads();
    const int tt = tid & 63, dg = tid >> 6;
    const float* xb = x + (size_t)b * (D_ * T_) + t0 + tt;
    float* qb = out_q + (size_t)b * (D_ * T_) + t0 + tt;
    float accm = 0.f;
    #pragma unroll 4
    for (int i = 0; i < 16; ++i) {
        const int dl = dg + i * 4;
        const int d = dq * 64 + dl;
        const float q  = cbs[tt][dl];
        const float xv = xb[(size_t)d * T_];
        qb[(size_t)d * T_] = xv + (q - xv);
        const float df = q - xv;
        accm = fmaf(df, df, accm);
    }
    red[tid] = accm;
    __syncthreads();
    for (int s = 128; s > 0; s >>= 1) {
        if (tid < s) red[tid] += red[tid + s];
        __syncthreads();
    }
    if (tid == 0) msep[blockIdx.x] = red[0];
}

// ------------------------------------------------------------------
// 5) finalize: losses + perplexity
// ------------------------------------------------------------------
__global__ __launch_bounds__(256) void finalize_k(const int* __restrict__ hist,
                                                  const float* __restrict__ msep,
                                                  float* __restrict__ scal) {
    __shared__ float redm[256];
    __shared__ float rede[256];
    const int tid = threadIdx.x;
    float e = 0.f;
    for (int k = tid; k < K_; k += 256) {
        const float p = (float)hist[k] * (1.0f / (float)N_);
        e += p * logf(p + 1e-10f);
    }
    rede[tid] = e;
    redm[tid] = ((msep[tid] + msep[tid + 256]) + (msep[tid + 512] + msep[tid + 768]));
    __syncthreads();
    for (int s = 128; s > 0; s >>= 1) {
        if (tid < s) { redm[tid] += redm[tid + s]; rede[tid] += rede[tid + s]; }
        __syncthreads();
    }
    if (tid == 0) {
        const float loss = redm[0] / (float)(B_ * D_ * T_);
        scal[0] = loss;
        scal[1] = loss;
        scal[2] = expf(-rede[0]);
    }
}

extern "C" void kernel_launch(void* const* d_in, const int* in_sizes, int n_in,
                              void* d_out, int out_size, void* d_ws, size_t ws_size,
                              hipStream_t stream) {
    const float* x  = (const float*)d_in[0];
    const float* cb = (const float*)d_in[1];

    float* out       = (float*)d_out;
    float* q_out     = out;                          // [B,D,T]
    float* codes_out = out + (size_t)B_ * D_ * T_;   // [B,T]
    float* scal      = codes_out + N_;               // 3 scalars

    _Float16* XhT = (_Float16*)d_ws;                 // N*D halves (8 MB)
    _Float16* ChT = XhT + (size_t)N_ * D_;           // K*D halves (4 MB)
    float* xT     = (float*)(ChT + (size_t)K_ * D_); // N*D floats (16 MB)
    float* xn     = xT + (size_t)N_ * D_;            // N
    int*   cntP   = (int*)(xn + N_);                 // N*8
    unsigned int* cand = (unsigned int*)(cntP + N_ * NPART);  // N*8*64 (33.5 MB)
    int*   hist   = (int*)(cand + (size_t)N_ * NPART * CAP_P);
    float* msep   = (float*)(hist + K_);             // 1024

    hipMemsetAsync(hist, 0, K_ * sizeof(int), stream);

    prep_k<<<1280, 256, 0, stream>>>(x, cb, XhT, ChT, xT, xn);
    argmin_mfma<<<128 * NPART, 256, 0, stream>>>(XhT, ChT, cntP, cand);
    rescore_k<<<N_ / 4, 256, 0, stream>>>(xT, cb, xn, cntP, cand, codes_out, hist);
    gather_k<<<1024, 256, 0, stream>>>(x, cb, codes_out, q_out, msep);
    finalize_k<<<1, 256, 0, stream>>>(hist, msep, scal);
}

// Round 14
// 153.778 us; speedup vs baseline: 2.0364x; 2.0364x over previous
//
#include <hip/hip_runtime.h>

#define B_ 8
#define D_ 256
#define T_ 2048
#define K_ 8192
#define N_ (B_*T_)              // 16384 tokens

typedef _Float16 half8 __attribute__((ext_vector_type(8)));
typedef float f32x4 __attribute__((ext_vector_type(4)));

constexpr int KPART  = 1024;          // codes per partition
constexpr int NPART  = 8;
constexpr int CAP_P  = 64;            // candidate slots per (token, partition)
constexpr float MARGIN = 6.0f;        // validated rounds 4-12 (cross-lane gate)
constexpr int   QTHR   = 78;          // rescore filter (9.75 * 8), validated
constexpr float CSCALE = 16384.0f;    // 2^14 codebook scale

// A image: 64-token chunks: q=n>>6 -> q*16384 + st*4096 + kb*512 + frag
// B image: 32-code chunks:  q=k>>5 -> q*8192 + ((k>>4)&1)*4096 + kb*512 + frag
// frag: ((d>>3)&3)*128 + row*8 + (d&7)   (16x16x32 f16 fragment order)

// ------------------------------------------------------------------
// 1) prep: blocks [0,256): xnorm + fp16(2x) A-image + xT fp32 rows
//          blocks [256,1280): fp16(c * 2^14) B fragment image
// ------------------------------------------------------------------
__global__ __launch_bounds__(256) void prep_k(const float* __restrict__ x,
                                              const float* __restrict__ cb,
                                              _Float16* __restrict__ Xh,
                                              _Float16* __restrict__ Ch,
                                              float* __restrict__ xT,
                                              float* __restrict__ xn) {
    const int tid = threadIdx.x;
    if (blockIdx.x >= 256) {
        const int task = (blockIdx.x - 256) * 256 + tid;   // K*32 tasks
        const int k = task >> 5, d0 = (task & 31) * 8;
        const float4 v0 = *(const float4*)(cb + (size_t)k * D_ + d0);
        const float4 v1 = *(const float4*)(cb + (size_t)k * D_ + d0 + 4);
        const float vv[8] = {v0.x, v0.y, v0.z, v0.w, v1.x, v1.y, v1.z, v1.w};
        half8 hi;
        #pragma unroll
        for (int j = 0; j < 8; ++j) hi[j] = (_Float16)(vv[j] * CSCALE);
        const size_t a = (size_t)(k >> 5) * 8192 + (size_t)((k >> 4) & 1) * 4096
                       + (size_t)(d0 >> 5) * 512
                       + (size_t)(((d0 >> 3) & 3) * 16 + (k & 15)) * 8;
        *(half8*)(Ch + a) = hi;
        return;
    }
    __shared__ float red[4][64];
    const int n0 = blockIdx.x * 64;          // one 64-token A-chunk per block
    const int b = n0 >> 11, t0 = n0 & 2047;
    const int tt = tid & 63, dg = tid >> 6;
    const int n = n0 + tt;
    const float* p = x + (size_t)b * (D_ * T_) + t0 + tt;
    _Float16* xbase = Xh + (size_t)blockIdx.x * 16384
                    + (size_t)((tt >> 4) & 3) * 4096 + (size_t)(tt & 15) * 8;
    float s = 0.f;
    for (int it = 0; it < 8; ++it) {
        const int d0 = dg * 64 + it * 8;
        float vv[8];
        half8 hi;
        #pragma unroll
        for (int j = 0; j < 8; ++j) {
            const float v = p[(size_t)(d0 + j) * T_];
            s = fmaf(v, v, s);
            vv[j] = v;
            hi[j] = (_Float16)(2.0f * v);
        }
        *(half8*)(xbase + (size_t)(d0 >> 5) * 512 + (size_t)((d0 >> 3) & 3) * 128) = hi;
        *(float4*)(xT + (size_t)n * D_ + d0)     = (float4){vv[0], vv[1], vv[2], vv[3]};
        *(float4*)(xT + (size_t)n * D_ + d0 + 4) = (float4){vv[4], vv[5], vv[6], vv[7]};
    }
    red[dg][tt] = s;
    __syncthreads();
    if (tid < 64) xn[n0 + tt] = (red[0][tt] + red[1][tt]) + (red[2][tt] + red[3][tt]);
}

// ------------------------------------------------------------------
// 2) main: r8 structure (64 tok/wave, wave-autonomous, 2 blk/CU) +
//    acc PING-PONG (MM of slice s overlaps EPI of slice s-1) +
//    LAG-1 threshold (shfl chain off the critical path; superset gate).
// ------------------------------------------------------------------
__global__ __launch_bounds__(256, 2) void argmin_mfma(const _Float16* __restrict__ XhT,
                                                      const _Float16* __restrict__ ChT,
                                                      int* __restrict__ cntP,
                                                      unsigned int* __restrict__ cand) {
    __shared__ int lcnt[256];

    const int tid = threadIdx.x;
    const int lane = tid & 63, wave = tid >> 6;
    const int l15 = lane & 15, l4 = lane >> 4;
    const int kp = blockIdx.x & 7;       // same-kp blocks -> same XCD (L2 affinity)
    const int tt = blockIdx.x >> 3;      // 64 token tiles of 256
    const int n0b = tt * 256;
    const int qA = tt * 4 + wave;        // wave's 64-token A chunk

    // ---- token fragments in registers: 64 tokens x 256 d ----
    half8 ah[4][8];
    #pragma unroll
    for (int st = 0; st < 4; ++st)
        #pragma unroll
        for (int kb = 0; kb < 8; ++kb)
            ah[st][kb] = *(const half8*)(XhT + (size_t)qA * 16384 + (size_t)st * 4096
                                         + (size_t)kb * 512 + (size_t)lane * 8);

    lcnt[tid] = 0;
    __syncthreads();

    float runmax[4];
    #pragma unroll
    for (int st = 0; st < 4; ++st) runmax[st] = -3.4e38f;

    const _Float16* cB = ChT + (size_t)(kp * 32) * 8192 + (size_t)lane * 8;

    auto LB = [&](half8* bf, size_t off) {
        #pragma unroll
        for (int kb = 0; kb < 8; ++kb)
            bf[kb] = *(const half8*)(cB + off + (size_t)kb * 512);
    };
    auto MM = [&](f32x4* acc, const half8* bf) {
        #pragma unroll
        for (int st = 0; st < 4; ++st) acc[st] = (f32x4){0.f, 0.f, 0.f, 0.f};
        __builtin_amdgcn_s_setprio(1);
        #pragma unroll
        for (int kb = 0; kb < 8; ++kb)
            #pragma unroll
            for (int st = 0; st < 4; ++st)
                acc[st] = __builtin_amdgcn_mfma_f32_16x16x32_f16(bf[kb], ah[st][kb], acc[st], 0, 0, 0);
        __builtin_amdgcn_s_setprio(0);
    };
    auto PUSH = [&](const f32x4* acc, int st, float thr, int s) {
        const int kbase = kp * KPART + s * 16 + l4 * 4;
        const int ltok = wave * 64 + st * 16 + l15;
        #pragma unroll
        for (int r = 0; r < 4; ++r) {
            const float v = acc[st][r];
            if (v >= thr) {
                const int pos = atomicAdd(&lcnt[ltok], 1);
                if (pos < CAP_P) {
                    int q = (int)floorf((v + 2048.0f) * 8.0f);
                    q = q < 0 ? 0 : (q > 32767 ? 32767 : q);
                    cand[((size_t)(kp * N_ + n0b + ltok)) * CAP_P + pos] =
                        ((unsigned int)q << 13) | (unsigned int)(kbase + r);
                }
            }
        }
    };
    // slice 0: self-gated (primes runmax; serial shfl once)
    auto EPI0 = [&](const f32x4* acc) {
        #pragma unroll
        for (int st = 0; st < 4; ++st) {
            const float lm = fmaxf(fmaxf(acc[st][0], acc[st][1]),
                                   fmaxf(acc[st][2], acc[st][3]));
            float m = fmaxf(lm, __shfl_xor(lm, 16));
            m = fmaxf(m, __shfl_xor(m, 32));
            runmax[st] = m;
            const float thr = m - MARGIN;
            if (lm >= thr) PUSH(acc, st, thr, 0);
        }
    };
    // steady state: gate with LAGGED runmax (through slice s-1); the shfl
    // reduce result is only needed one slice later -> hidden under next MM.
    auto EPI = [&](const f32x4* acc, int s) {
        #pragma unroll
        for (int st = 0; st < 4; ++st) {
            const float lm = fmaxf(fmaxf(acc[st][0], acc[st][1]),
                                   fmaxf(acc[st][2], acc[st][3]));
            const float thr = runmax[st] - MARGIN;   // lagged: superset gate
            if (lm >= thr) PUSH(acc, st, thr, s);
            float m = fmaxf(lm, __shfl_xor(lm, 16));
            m = fmaxf(m, __shfl_xor(m, 32));
            runmax[st] = fmaxf(runmax[st], m);
        }
    };

    half8 bA[8], bB[8];
    f32x4 accA[4], accB[4];              // ping-pong: MM(s) || EPI(s-1)
    LB(bA, 0);
    LB(bB, 4096);
    MM(accA, bA);                        // slice 0
    EPI0(accA);
    LB(bA, 2 * 4096);
    MM(accB, bB);                        // slice 1
    for (int g = 1; g <= 30; ++g) {
        LB(bB, (size_t)(2 * g + 1) * 4096);
        MM(accA, bA);                    // slice 2g
        EPI(accB, 2 * g - 1);            // finish slice 2g-1 (overlaps MM above)
        LB(bA, (size_t)(2 * g + 2) * 4096);
        MM(accB, bB);                    // slice 2g+1
        EPI(accA, 2 * g);                // finish slice 2g
    }
    LB(bB, (size_t)63 * 4096);
    MM(accA, bA);                        // slice 62
    EPI(accB, 61);
    MM(accB, bB);                        // slice 63
    EPI(accA, 62);
    EPI(accB, 63);

    __syncthreads();
    cntP[kp * N_ + n0b + tid] = lcnt[tid];
}

// ------------------------------------------------------------------
// 3) rescore: lane-parallel candidate load (slot==lane), qmax filter,
//    ballot-compacted survivors, exact fp32 fl(xnorm - dot2), tie->lowest k
// ------------------------------------------------------------------
__global__ __launch_bounds__(256) void rescore_k(const float* __restrict__ xT,
                                                 const float* __restrict__ cb,
                                                 const float* __restrict__ xn,
                                                 const int* __restrict__ cntP,
                                                 const unsigned int* __restrict__ cand,
                                                 float* __restrict__ codes_out,
                                                 int* __restrict__ hist) {
    const int tid = threadIdx.x, lane = tid & 63, wave = tid >> 6;
    const int n = blockIdx.x * 4 + wave;     // one wave per token
    float xv[4];
    #pragma unroll
    for (int j = 0; j < 4; ++j) xv[j] = 2.0f * xT[(size_t)n * D_ + lane + j * 64];
    const float xnr = xn[n];

    unsigned int w[NPART];
    int mc[NPART];
    int qm = 0;
    #pragma unroll
    for (int kp = 0; kp < NPART; ++kp) {
        int m = cntP[kp * N_ + n]; m = m > CAP_P ? CAP_P : m;
        mc[kp] = m;
        unsigned int v = 0;
        if (lane < m) v = cand[((size_t)(kp * N_ + n)) * CAP_P + lane];   // coalesced
        w[kp] = v;
        const int q = (int)(v >> 13);
        qm = q > qm ? q : qm;
    }
    #pragma unroll
    for (int s = 1; s < 64; s <<= 1) {
        const int o = __shfl_xor(qm, s);
        qm = o > qm ? o : qm;
    }
    const int qthr = qm - QTHR;

    float bs = 3.4e38f; int bk = 0x7fffffff;
    #pragma unroll
    for (int kp = 0; kp < NPART; ++kp) {
        unsigned long long mask = __ballot(lane < mc[kp] && (int)(w[kp] >> 13) >= qthr);
        while (mask) {
            const int j = __builtin_ctzll(mask);
            mask &= mask - 1;
            const unsigned int pk = __shfl(w[kp], j);
            const int k = (int)(pk & 8191u);
            const float* cr = cb + (size_t)k * D_;
            float p = 0.f;
            #pragma unroll
            for (int j2 = 0; j2 < 4; ++j2) p = fmaf(xv[j2], cr[lane + j2 * 64], p);
            #pragma unroll
            for (int s = 1; s < 64; s <<= 1) p += __shfl_xor(p, s);
            const float sc = xnr - p;
            if (sc < bs || (sc == bs && k < bk)) { bs = sc; bk = k; }
        }
    }
    if (lane == 0) {
        codes_out[n] = (float)bk;
        atomicAdd(&hist[bk], 1);
    }
}

// ------------------------------------------------------------------
// 4) gather quantized (+ straight-through x+(q-x)), MSE partials.
//    Codebook rows staged in LDS (coalesced) to kill scattered gathers.
// ------------------------------------------------------------------
__global__ __launch_bounds__(256) void gather_k(const float* __restrict__ x,
                                                const float* __restrict__ cb,
                                                const float* __restrict__ codes_f,
                                                float* __restrict__ out_q,
                                                float* __restrict__ msep) {
    __shared__ int codes_s[64];
    __shared__ float cbs[64][65];
    __shared__ float red[256];
    const int tq = blockIdx.x >> 2;      // token 64-chunk
    const int dq = blockIdx.x & 3;       // d quarter (64 d's)
    const int n0 = tq * 64;
    const int b = n0 >> 11, t0 = n0 & 2047;
    const int tid = threadIdx.x;
    if (tid < 64) codes_s[tid] = (int)codes_f[n0 + tid];
    __syncthreads();
    {
        const int rr0 = tid >> 4, c4 = (tid & 15) * 4;
        #pragma unroll
        for (int rr = rr0; rr < 64; rr += 16) {
            const float4 v = *(const float4*)(cb + (size_t)codes_s[rr] * D_ + dq * 64 + c4);
            cbs[rr][c4 + 0] = v.x; cbs[rr][c4 + 1] = v.y;
            cbs[rr][c4 + 2] = v.z; cbs[rr][c4 + 3] = v.w;
        }
    }
    __syncthreads();
    const int tt = tid & 63, dg = tid >> 6;
    const float* xb = x + (size_t)b * (D_ * T_) + t0 + tt;
    float* qb = out_q + (size_t)b * (D_ * T_) + t0 + tt;
    float accm = 0.f;
    #pragma unroll 4
    for (int i = 0; i < 16; ++i) {
        const int dl = dg + i * 4;
        const int d = dq * 64 + dl;
        const float q  = cbs[tt][dl];
        const float xv = xb[(size_t)d * T_];
        qb[(size_t)d * T_] = xv + (q - xv);
        const float df = q - xv;
        accm = fmaf(df, df, accm);
    }
    red[tid] = accm;
    __syncthreads();
    for (int s = 128; s > 0; s >>= 1) {
        if (tid < s) red[tid] += red[tid + s];
        __syncthreads();
    }
    if (tid == 0) msep[blockIdx.x] = red[0];
}

// ------------------------------------------------------------------
// 5) finalize: losses + perplexity
// ------------------------------------------------------------------
__global__ __launch_bounds__(256) void finalize_k(const int* __restrict__ hist,
                                                  const float* __restrict__ msep,
                                                  float* __restrict__ scal) {
    __shared__ float redm[256];
    __shared__ float rede[256];
    const int tid = threadIdx.x;
    float e = 0.f;
    for (int k = tid; k < K_; k += 256) {
        const float p = (float)hist[k] * (1.0f / (float)N_);
        e += p * logf(p + 1e-10f);
    }
    rede[tid] = e;
    redm[tid] = ((msep[tid] + msep[tid + 256]) + (msep[tid + 512] + msep[tid + 768]));
    __syncthreads();
    for (int s = 128; s > 0; s >>= 1) {
        if (tid < s) { redm[tid] += redm[tid + s]; rede[tid] += rede[tid + s]; }
        __syncthreads();
    }
    if (tid == 0) {
        const float loss = redm[0] / (float)(B_ * D_ * T_);
        scal[0] = loss;
        scal[1] = loss;
        scal[2] = expf(-rede[0]);
    }
}

extern "C" void kernel_launch(void* const* d_in, const int* in_sizes, int n_in,
                              void* d_out, int out_size, void* d_ws, size_t ws_size,
                              hipStream_t stream) {
    const float* x  = (const float*)d_in[0];
    const float* cb = (const float*)d_in[1];

    float* out       = (float*)d_out;
    float* q_out     = out;                          // [B,D,T]
    float* codes_out = out + (size_t)B_ * D_ * T_;   // [B,T]
    float* scal      = codes_out + N_;               // 3 scalars

    _Float16* XhT = (_Float16*)d_ws;                 // N*D halves (8 MB)
    _Float16* ChT = XhT + (size_t)N_ * D_;           // K*D halves (4 MB)
    float* xT     = (float*)(ChT + (size_t)K_ * D_); // N*D floats (16 MB)
    float* xn     = xT + (size_t)N_ * D_;            // N
    int*   cntP   = (int*)(xn + N_);                 // N*8
    unsigned int* cand = (unsigned int*)(cntP + N_ * NPART);  // N*8*64 (33.5 MB)
    int*   hist   = (int*)(cand + (size_t)N_ * NPART * CAP_P);
    float* msep   = (float*)(hist + K_);             // 1024

    hipMemsetAsync(hist, 0, K_ * sizeof(int), stream);

    prep_k<<<1280, 256, 0, stream>>>(x, cb, XhT, ChT, xT, xn);
    argmin_mfma<<<64 * NPART, 256, 0, stream>>>(XhT, ChT, cntP, cand);
    rescore_k<<<N_ / 4, 256, 0, stream>>>(xT, cb, xn, cntP, cand, codes_out, hist);
    gather_k<<<1024, 256, 0, stream>>>(x, cb, codes_out, q_out, msep);
    finalize_k<<<1, 256, 0, stream>>>(hist, msep, scal);
}